// Round 8
// baseline (40604.187 us; speedup 1.0000x reference)
//
#include <hip/hip_runtime.h>

// AlphatRNN B=128,T=512,D=256,H=1024,L=2,O=1 — bf16 MFMA persistent kernel, R8.
// R8: geometry attack on the sc1 read amplification (no cache-semantics bets).
// 64 WGs x 512 thr; WG tile = 16 rows x 128 cols; 8 waves = 8 K-eighths (no
// duplicate A reads). Each wave loads its A-quarter once (registers) and
// streams 8 weight col-tiles over it (weights L2-hot via ng=wg&7 XCD match).
// Slice traffic/step: 256WGx64KB -> 64WGx32KB (8x cut), all via proven sc1
// agent loads. 8-deep reduce in conflict-free scalar planes (skip-own packed).
// Phase/dataflow/math = R6 (passing): 2 barriers/step, partial pipelining.

typedef unsigned short u16;
typedef unsigned long long u64;
typedef __attribute__((ext_vector_type(8))) short short8;
typedef __attribute__((ext_vector_type(4))) float f32x4;

#define NB   128
#define TT   512
#define DD   256
#define HH   1024
#define NWG  64
#define NTHR 512
#define SPAN (NB * HH)

// ---- ws layout (bytes) ----
#define S0_OFF  0u          // bf16 [2][128][1024] (parity double buffer)
#define S1_OFF  524288u     // bf16 [128][1024]
#define H0_OFF  786432u     // bf16 [128][1024]
#define CTR_OFF 1048576u    // 1024 barids x 128 B
#define W_OFF   1179648u    // bf16 weights: 6x[1024][1024], then [1024][256]x2
#define NBIG    6291456u    // 6 * 1048576

__device__ __forceinline__ u16 f2bf(float f) {   // RNE, finite inputs only
    unsigned u = __builtin_bit_cast(unsigned, f);
    return (u16)((u + 0x7fffu + ((u >> 16) & 1u)) >> 16);
}

__device__ __forceinline__ u64 agent_load64(const u64* p) {
    return __hip_atomic_load(p, __ATOMIC_RELAXED, __HIP_MEMORY_SCOPE_AGENT);
}
__device__ __forceinline__ void agent_store16(u16* p, u16 v) {
    __hip_atomic_store(p, v, __ATOMIC_RELAXED, __HIP_MEMORY_SCOPE_AGENT);
}

// Global 64-WG barrier; fresh 128B-padded counter per barid (memset each launch).
// Leading __syncthreads drains every wave's sc1 stores (vmcnt0 before s_barrier).
__device__ __forceinline__ void gbar(char* cb, int& barid)
{
    __syncthreads();
    if (threadIdx.x == 0) {
        unsigned* c = (unsigned*)(cb + (size_t)barid * 128);
        __hip_atomic_fetch_add(c, 1u, __ATOMIC_RELEASE, __HIP_MEMORY_SCOPE_AGENT);
        while (__hip_atomic_load(c, __ATOMIC_RELAXED, __HIP_MEMORY_SCOPE_AGENT) != NWG)
            __builtin_amdgcn_s_sleep(1);
    }
    ++barid;
    __syncthreads();
}

// A-frags for one K-eighth: lane(lrow,lkg) reads row, k = kq*128 + s*32 + lkg*8,
// s=0..3. 4x short8 per lane, direct from published span via sc1.
__device__ __forceinline__ void load_frags(short8* fr, const u16* base,
                                           int row, int kq, int lkg)
{
    const u16* sp = base + ((size_t)row << 10) + kq * 128 + lkg * 8;
    #pragma unroll
    for (int s = 0; s < 4; ++s) {
        union { short8 v; u64 q[2]; } u_;
        u_.q[0] = agent_load64((const u64*)(sp + s * 32));
        u_.q[1] = agent_load64((const u64*)(sp + s * 32 + 4));
        fr[s] = u_.v;
    }
}

// acc[nc] += A(frags) @ W[n0+nc*16.., K-eighth]^T for 8 col-tiles (in place).
// Weights: plain loads, L2-resident (per-XCD 1.5MB slice via ng=wg&7).
__device__ __forceinline__ void mmH(f32x4* acc, const short8* fr, const u16* W,
                                    int n0, int kq, int lrow, int lkg)
{
    #pragma unroll
    for (int nc = 0; nc < 8; ++nc) {
        const u16* wp = W + ((size_t)(n0 + nc * 16 + lrow) << 10) + kq * 128 + lkg * 8;
        #pragma unroll
        for (int s = 0; s < 4; ++s)
            acc[nc] = __builtin_amdgcn_mfma_f32_16x16x32_bf16(
                fr[s], *(const short8*)(wp + s * 32), acc[nc], 0, 0, 0);
    }
}

// acc[nc] += x_row(fp32->bf16 in reg) @ Wx[n0+nc*16.., K-eighth of 256]^T.
__device__ __forceinline__ void mmX(f32x4* acc, const float* xrow, const u16* W,
                                    int n0, int kq, int lrow, int lkg)
{
    const float* p = xrow + kq * 32 + lkg * 8;
    float4 a = *(const float4*)p;
    float4 b = *(const float4*)(p + 4);
    short8 v;
    v[0]=(short)f2bf(a.x); v[1]=(short)f2bf(a.y); v[2]=(short)f2bf(a.z); v[3]=(short)f2bf(a.w);
    v[4]=(short)f2bf(b.x); v[5]=(short)f2bf(b.y); v[6]=(short)f2bf(b.z); v[7]=(short)f2bf(b.w);
    #pragma unroll
    for (int nc = 0; nc < 8; ++nc) {
        const u16* wp = W + ((size_t)(n0 + nc * 16 + lrow) << 8) + kq * 32 + lkg * 8;
        acc[nc] = __builtin_amdgcn_mfma_f32_16x16x32_bf16(
            v, *(const short8*)wp, acc[nc], 0, 0, 0);
    }
}

// 8-deep WG reduce. Wave kq owns col-tile kq. Scalar planes (4B lane stride,
// conflict-free), skip-own packed [4][8 tiles][7 partials][64]. Own-tile value
// extracted with an unrolled predicated select (no runtime reg-array index).
__device__ __forceinline__ f32x4 wred(float (*red)[8][7][64], const f32x4* acc,
                                      int kq, int lane)
{
    __syncthreads();   // WAR vs previous reduce's readers
    #pragma unroll
    for (int nc = 0; nc < 8; ++nc) {
        if (nc != kq) {
            int j = (kq < nc) ? kq : kq - 1;
            #pragma unroll
            for (int c = 0; c < 4; ++c) red[c][nc][j][lane] = acc[nc][c];
        }
    }
    __syncthreads();
    f32x4 own = {0.f, 0.f, 0.f, 0.f};
    #pragma unroll
    for (int nc = 0; nc < 8; ++nc) if (nc == kq) own = acc[nc];
    #pragma unroll
    for (int j = 0; j < 7; ++j)
        #pragma unroll
        for (int c = 0; c < 4; ++c) own[c] += red[c][kq][j][lane];
    return own;
}

__global__ void conv_weights(const float* Uas0, const float* Whh0, const float* Wax1,
                             const float* Uas1, const float* Wih1, const float* Whh1,
                             const float* Wax0, const float* Wih0, u16* dst)
{
    for (size_t i = (size_t)blockIdx.x * blockDim.x + threadIdx.x; i < 6815744u;
         i += (size_t)gridDim.x * blockDim.x) {
        const float* src; size_t off;
        if (i < NBIG) {
            int seg = (int)(i >> 20); off = i & 1048575u;
            src = seg == 0 ? Uas0 : seg == 1 ? Whh0 : seg == 2 ? Wax1
                : seg == 3 ? Uas1 : seg == 4 ? Wih1 : Whh1;
        } else {
            size_t j = i - NBIG; off = j & 262143u;
            src = (j >> 18) ? Wih0 : Wax0;
        }
        dst[i] = f2bf(src[off]);
    }
}

extern "C" __global__ void __launch_bounds__(NTHR, 1)
alphat_mfma(const float* __restrict__ x,
            const u16* __restrict__ wUas0, const u16* __restrict__ wWhh0,
            const u16* __restrict__ wWax1, const u16* __restrict__ wUas1,
            const u16* __restrict__ wWih1, const u16* __restrict__ wWhh1,
            const u16* __restrict__ wWax0, const u16* __restrict__ wWih0,
            const float* __restrict__ ba0, const float* __restrict__ bh0,
            const float* __restrict__ ba1, const float* __restrict__ bh1,
            const float* __restrict__ fcW, const float* __restrict__ fcb,
            float* __restrict__ out,
            u16* s0b, u16* s1b, u16* h0b, char* ctr)
{
    __shared__ float red[4][8][7][64];   // 57344 B reduce planes (only LDS)

    const int tid  = threadIdx.x;
    const int kq   = tid >> 6;        // wave = K-eighth AND owned col-tile
    const int lane = tid & 63;
    const int lrow = lane & 15;
    const int lkg  = lane >> 4;

    const int wg = blockIdx.x;
    const int ng = wg & 7;            // XCD-matched col-slice (round-robin dispatch)
    const int mg = wg >> 3;           // batch row-block
    const int m0 = mg * 16;
    const int n0 = ng * 128;

    const int gcol  = n0 + kq * 16 + lrow;   // owned C col (= weight row base use)
    const int grow0 = m0 + lkg * 4;          // owned C rows base
    const int arow  = m0 + lrow;             // A-frag source row

    const float vba0 = ba0[gcol], vbh0 = bh0[gcol];
    const float vba1 = ba1[gcol], vbh1 = bh1[gcol];

    const f32x4 zf = {0.f, 0.f, 0.f, 0.f};
    float h0l[4] = {0,0,0,0}, s0l[4] = {0,0,0,0};
    float h1l[4] = {0,0,0,0}, s1l[4] = {0,0,0,0};
    int barid = 0;

    // ---- prologue: s0(0)=0 -> zero frags; x partials for t=0 (B) and t=1 (alpha0)
    short8 frags[4];
    #pragma unroll
    for (int s = 0; s < 4; ++s)
        #pragma unroll
        for (int i = 0; i < 8; ++i) frags[s][i] = 0;
    const float* xbase = x + (size_t)arow * (TT * DD);

    f32x4 pBx[8], pAxN[8], pC1[8], pD1[8];
    #pragma unroll
    for (int nc = 0; nc < 8; ++nc) { pBx[nc] = zf; pAxN[nc] = zf; pC1[nc] = zf; }
    mmX(pBx,  xbase + 0 * DD, wWih0, n0, kq, lrow, lkg);   // Wih0 x_0
    mmX(pAxN, xbase + 1 * DD, wWax0, n0, kq, lrow, lkg);   // Wax0 x_1

    for (int t = 0; t < TT; ++t) {
        u16* s0nxt = s0b + ((t + 1) & 1) * SPAN;

        // ---- B: h0(t)=tanh(pBx + Whh0 s0(t) + bh0); alpha0(t+1)=sig(pAxN +
        //      Uas0 s0(t) + ba0); s0(t+1)=a*h0+(1-a)*s0. Publish h0, s0(t+1).
        //      frags = s0(t) (prefetched in D(t-1); zeros at t=0).
        mmH(pBx,  frags, wWhh0, n0, kq, lrow, lkg);
        mmH(pAxN, frags, wUas0, n0, kq, lrow, lkg);
        f32x4 hac = wred(red, pBx,  kq, lane);
        f32x4 aac = wred(red, pAxN, kq, lane);
        #pragma unroll
        for (int r = 0; r < 4; ++r) {
            float hn = tanhf(hac[r] + vbh0);
            agent_store16(h0b + (size_t)(grow0 + r) * HH + gcol, f2bf(hn));
            if (t + 1 < TT) {
                float al = 1.f / (1.f + __expf(-(aac[r] + vba0)));
                float sn = al * hn + (1.f - al) * s0l[r];
                s0l[r] = sn;
                agent_store16(s0nxt + (size_t)(grow0 + r) * HH + gcol, f2bf(sn));
            }
            h0l[r] = hn;
        }
        gbar(ctr, barid);

        // ---- C: alpha1(t)=sig(pC1 + Wax1 h0 + ba1); s1(t)=a1*h1(t-1)+(1-a1)*s1(t-1);
        //      publish s1(t). pD1 = Wih1 h0 (partial, reduced in D).
        short8 fh[4];
        load_frags(fh, h0b, arow, kq, lkg);
        mmH(pC1, fh, wWax1, n0, kq, lrow, lkg);
        #pragma unroll
        for (int nc = 0; nc < 8; ++nc) pD1[nc] = zf;
        mmH(pD1, fh, wWih1, n0, kq, lrow, lkg);
        f32x4 cac = wred(red, pC1, kq, lane);
        #pragma unroll
        for (int r = 0; r < 4; ++r) {
            float al = 1.f / (1.f + __expf(-(cac[r] + vba1)));
            float sn = al * h1l[r] + (1.f - al) * s1l[r];
            s1l[r] = sn;
            agent_store16(s1b + (size_t)(grow0 + r) * HH + gcol, f2bf(sn));
        }
        gbar(ctr, barid);

        // ---- D: h1(t)=tanh(pD1 + Whh1 s1 + bh1); pC1 = Uas1 s1 (for C(t+1));
        //      prefetch s0(t+1) frags; x partials for t+1 / t+2.
        short8 fs1[4];
        load_frags(fs1, s1b, arow, kq, lkg);
        if (t + 1 < TT) load_frags(frags, s0nxt, arow, kq, lkg);
        mmH(pD1, fs1, wWhh1, n0, kq, lrow, lkg);
        #pragma unroll
        for (int nc = 0; nc < 8; ++nc) pC1[nc] = zf;
        mmH(pC1, fs1, wUas1, n0, kq, lrow, lkg);
        if (t + 1 < TT) {
            #pragma unroll
            for (int nc = 0; nc < 8; ++nc) pBx[nc] = zf;
            mmX(pBx, xbase + (size_t)(t + 1) * DD, wWih0, n0, kq, lrow, lkg);
        }
        if (t + 2 < TT) {
            #pragma unroll
            for (int nc = 0; nc < 8; ++nc) pAxN[nc] = zf;
            mmX(pAxN, xbase + (size_t)(t + 2) * DD, wWax0, n0, kq, lrow, lkg);
        }
        f32x4 dac = wred(red, pD1, kq, lane);
        #pragma unroll
        for (int r = 0; r < 4; ++r) h1l[r] = tanhf(dac[r] + vbh1);
        // no trailing barrier: B(t+1)'s wred leading __syncthreads covers red
        // WAR; frags are register-resident; all span WAR windows span >=1 gbar.
    }

    // ---- epilogue: every thread owns 4 elements (rows grow0+r, col gcol) ----
    {
        const size_t HIDB = NB, SMOB = NB + 2 * (size_t)SPAN;
        #pragma unroll
        for (int r = 0; r < 4; ++r) {
            size_t o = (size_t)(grow0 + r) * HH + gcol;
            out[HIDB + o]        = h0l[r];
            out[HIDB + SPAN + o] = h1l[r];
            out[SMOB + o]        = s0l[r];
            out[SMOB + SPAN + o] = s1l[r];
        }
        // out[b] = sum_n h1[b,n]*fcW[n] + fcb  (16-col partial per wave rowgroup)
        #pragma unroll
        for (int r = 0; r < 4; ++r) {
            float v = h1l[r] * fcW[gcol];
            v += __shfl_xor(v, 1); v += __shfl_xor(v, 2);
            v += __shfl_xor(v, 4); v += __shfl_xor(v, 8);
            if (lrow == 0) {
                if (ng == 0 && kq == 0) v += fcb[0];
                atomicAdd(out + grow0 + r, v);
            }
        }
    }
}

extern "C" void kernel_launch(void* const* d_in, const int* in_sizes, int n_in,
                              void* d_out, int out_size, void* d_ws, size_t ws_size,
                              hipStream_t stream)
{
    const float* x    = (const float*)d_in[0];
    const float* Wax0 = (const float*)d_in[1];
    const float* Uas0 = (const float*)d_in[2];
    const float* ba0  = (const float*)d_in[3];
    const float* Wih0 = (const float*)d_in[4];
    const float* Whh0 = (const float*)d_in[5];
    const float* bh0  = (const float*)d_in[6];
    const float* Wax1 = (const float*)d_in[7];
    const float* Uas1 = (const float*)d_in[8];
    const float* ba1  = (const float*)d_in[9];
    const float* Wih1 = (const float*)d_in[10];
    const float* Whh1 = (const float*)d_in[11];
    const float* bh1  = (const float*)d_in[12];
    const float* fcW  = (const float*)d_in[13];
    const float* fcb  = (const float*)d_in[14];
    float* out = (float*)d_out;

    char* ws = (char*)d_ws;
    u16* s0b = (u16*)(ws + S0_OFF);
    u16* s1b = (u16*)(ws + S1_OFF);
    u16* h0b = (u16*)(ws + H0_OFF);
    char* ctr = ws + CTR_OFF;
    u16* wbase = (u16*)(ws + W_OFF);
    u16* wUas0 = wbase + 0 * 1048576;
    u16* wWhh0 = wbase + 1 * 1048576;
    u16* wWax1 = wbase + 2 * 1048576;
    u16* wUas1 = wbase + 3 * 1048576;
    u16* wWih1 = wbase + 4 * 1048576;
    u16* wWhh1 = wbase + 5 * 1048576;
    u16* wWax0 = wbase + 6 * 1048576;
    u16* wWih0 = wbase + 6 * 1048576 + 262144;

    // zero state spans + barrier counters + output (accumulated via atomics)
    hipMemsetAsync(d_ws, 0, W_OFF, stream);
    hipMemsetAsync(d_out, 0, (size_t)out_size * sizeof(float), stream);

    conv_weights<<<dim3(1024), dim3(256), 0, stream>>>(
        Uas0, Whh0, Wax1, Uas1, Wih1, Whh1, Wax0, Wih0, wbase);

    alphat_mfma<<<dim3(NWG), dim3(NTHR), 0, stream>>>(
        x, wUas0, wWhh0, wWax1, wUas1, wWih1, wWhh1, wWax0, wWih0,
        ba0, bh0, ba1, bh1, fcW, fcb, out, s0b, s1b, h0b, ctr);
}

// Round 10
// 17510.696 us; speedup vs baseline: 2.3188x; 2.3188x over previous
//
#include <hip/hip_runtime.h>

// AlphatRNN B=128,T=512,D=256,H=1024,L=2,O=1 — bf16 MFMA persistent kernel, R10.
// R10 = R9 with the layout bug fixed: mm_x now ALSO uses swapped operand order
// (mfma(W_frag, x_frag)) so every accumulator lives in the same D layout
// (rows = weight rows / H-cols, cols = batch). R9 mixed two layouts -> garbage.
//  (1) group-local producer FLAGS instead of counter barriers: each of the 32
//      same-mg WGs stores a monotonic value (t+1) to its own 64B-padded flag;
//      consumers poll all 32 flags in parallel lanes (no RMW serialization).
//  (2) swapped MFMA operands: each lane owns 4 CONSECUTIVE H-cols of one batch
//      row -> publications are single 8B agent stores.

typedef unsigned short u16;
typedef unsigned long long u64;
typedef __attribute__((ext_vector_type(8))) short short8;
typedef __attribute__((ext_vector_type(4))) float f32x4;

#define NB   128
#define TT   512
#define DD   256
#define HH   1024
#define NWG  256
#define NTHR 512
#define SPAN (NB * HH)

// ---- ws layout (bytes) ----
#define S0_OFF  0u          // bf16 [2][128][1024] (parity double buffer)
#define S1_OFF  524288u     // bf16 [128][1024]
#define H0_OFF  786432u     // bf16 [128][1024]
#define FL_OFF  1048576u    // 2 flag arrays x [8 mg][32 wgl] x 64 B = 32 KB
#define W_OFF   1081344u    // bf16 weights: 6x[1024][1024], then [1024][256]x2
#define NBIG    6291456u    // 6 * 1048576

__device__ __forceinline__ u16 f2bf(float f) {   // RNE, finite inputs only
    unsigned u = __builtin_bit_cast(unsigned, f);
    return (u16)((u + 0x7fffu + ((u >> 16) & 1u)) >> 16);
}

__device__ __forceinline__ u64 agent_load64(const u64* p) {
    return __hip_atomic_load(p, __ATOMIC_RELAXED, __HIP_MEMORY_SCOPE_AGENT);
}
__device__ __forceinline__ void agent_store64(u64* p, u64 v) {
    __hip_atomic_store(p, v, __ATOMIC_RELAXED, __HIP_MEMORY_SCOPE_AGENT);
}

// Producer flag set: __syncthreads drains the publishing waves' sc1 stores
// (vmcnt0 before s_barrier), then one RELEASE store of the step value.
__device__ __forceinline__ void flag_set(unsigned* f, int wgl, unsigned val, int tid)
{
    __syncthreads();
    if (tid == 0)
        __hip_atomic_store(f + wgl * 16, val, __ATOMIC_RELEASE,
                           __HIP_MEMORY_SCOPE_AGENT);
}
// Consumer: lanes 0..31 poll the 32 group flags in parallel (monotonic >= val).
__device__ __forceinline__ void flag_wait(unsigned* f, unsigned val, int tid)
{
    if (tid < 32)
        while (__hip_atomic_load(f + tid * 16, __ATOMIC_RELAXED,
                                 __HIP_MEMORY_SCOPE_AGENT) < val)
            __builtin_amdgcn_s_sleep(1);
    __syncthreads();
}

// B-operand state frags for one K-quarter: lane(lrow,lkg) reads row m0+lrow,
// k = kq*256 + s*32 + lkg*8, s=0..7. Direct from published span via sc1.
__device__ __forceinline__ void load_frags(short8* fr, const u16* base,
                                           int row, int kq, int lkg)
{
    const u16* sp = base + ((size_t)row << 10) + kq * 256 + lkg * 8;
    #pragma unroll
    for (int s = 0; s < 8; ++s) {
        union { short8 v; u64 q[2]; } u_;
        u_.q[0] = agent_load64((const u64*)(sp + s * 32));
        u_.q[1] = agent_load64((const u64*)(sp + s * 32 + 4));
        fr[s] = u_.v;
    }
}

// acc += W[wr, kq-quarter] (x) S(frags), SWAPPED: D rows = W rows (H-cols),
// D cols = S rows (batch). Weight loads plain (L2-resident slice).
template<int NS>
__device__ __forceinline__ f32x4 mm_reg(f32x4 acc, const short8* fr, const u16* W,
                                        int wr, int kq, int lkg)
{
    const u16* wp = W + ((size_t)wr << 10) + kq * 256 + lkg * 8;
    #pragma unroll
    for (int s = 0; s < NS; ++s)
        acc = __builtin_amdgcn_mfma_f32_16x16x32_bf16(
            *(const short8*)(wp + s * 32), fr[s], acc, 0, 0, 0);
    return acc;
}

// acc += Wx[wr, kq-quarter of 256] (x) x_row(fp32->bf16 in reg), SWAPPED
// (R10 fix: weight frag is the A-operand here too).
__device__ __forceinline__ f32x4 mm_x(f32x4 acc, const float* xrow, const u16* W,
                                      int wr, int kq, int lkg)
{
    #pragma unroll
    for (int s = 0; s < 2; ++s) {
        const float* p = xrow + kq * 64 + s * 32 + lkg * 8;
        float4 a = *(const float4*)p;
        float4 b = *(const float4*)(p + 4);
        short8 v;
        v[0]=(short)f2bf(a.x); v[1]=(short)f2bf(a.y); v[2]=(short)f2bf(a.z); v[3]=(short)f2bf(a.w);
        v[4]=(short)f2bf(b.x); v[5]=(short)f2bf(b.y); v[6]=(short)f2bf(b.z); v[7]=(short)f2bf(b.w);
        const u16* wp = W + ((size_t)wr << 8) + kq * 64 + s * 32 + lkg * 8;
        acc = __builtin_amdgcn_mfma_f32_16x16x32_bf16(
            *(const short8*)wp, v, acc, 0, 0, 0);
    }
    return acc;
}

// K-quarter reduce planes: 4B lane stride, conflict-free.
__device__ __forceinline__ void red_put(float (*red)[3][2][64], int p, f32x4 v,
                                        int nt, int kq, int lane)
{
    if (kq) {
        #pragma unroll
        for (int c = 0; c < 4; ++c) red[p + c][kq - 1][nt][lane] = v[c];
    }
}
__device__ __forceinline__ f32x4 red_get(float (*red)[3][2][64], int p, f32x4 v,
                                         int nt, int lane)
{
    #pragma unroll
    for (int c = 0; c < 4; ++c)
        v[c] += red[p + c][0][nt][lane] + red[p + c][1][nt][lane]
              + red[p + c][2][nt][lane];
    return v;
}

__device__ __forceinline__ u64 pack4(float a, float b, float c, float d)
{
    return (u64)f2bf(a) | ((u64)f2bf(b) << 16) | ((u64)f2bf(c) << 32)
         | ((u64)f2bf(d) << 48);
}

__global__ void conv_weights(const float* Uas0, const float* Whh0, const float* Wax1,
                             const float* Uas1, const float* Wih1, const float* Whh1,
                             const float* Wax0, const float* Wih0, u16* dst)
{
    for (size_t i = (size_t)blockIdx.x * blockDim.x + threadIdx.x; i < 6815744u;
         i += (size_t)gridDim.x * blockDim.x) {
        const float* src; size_t off;
        if (i < NBIG) {
            int seg = (int)(i >> 20); off = i & 1048575u;
            src = seg == 0 ? Uas0 : seg == 1 ? Whh0 : seg == 2 ? Wax1
                : seg == 3 ? Uas1 : seg == 4 ? Wih1 : Whh1;
        } else {
            size_t j = i - NBIG; off = j & 262143u;
            src = (j >> 18) ? Wih0 : Wax0;
        }
        dst[i] = f2bf(src[off]);
    }
}

extern "C" __global__ void __launch_bounds__(NTHR, 1)
alphat_mfma(const float* __restrict__ x,
            const u16* __restrict__ wUas0, const u16* __restrict__ wWhh0,
            const u16* __restrict__ wWax1, const u16* __restrict__ wUas1,
            const u16* __restrict__ wWih1, const u16* __restrict__ wWhh1,
            const u16* __restrict__ wWax0, const u16* __restrict__ wWih0,
            const float* __restrict__ ba0, const float* __restrict__ bh0,
            const float* __restrict__ ba1, const float* __restrict__ bh1,
            const float* __restrict__ fcW, const float* __restrict__ fcb,
            float* __restrict__ out,
            u16* s0b, u16* s1b, u16* h0b, unsigned* flags)
{
    __shared__ float red[8][3][2][64];           // 12 KB reduce planes (only LDS)

    const int tid  = threadIdx.x;
    const int wv   = tid >> 6;
    const int lane = tid & 63;
    const int nt   = wv & 1;          // n-tile 0/1
    const int kq   = wv >> 1;         // K-quarter 0..3
    const int lrow = lane & 15;
    const int lkg  = lane >> 4;

    const int wg  = blockIdx.x;
    const int ng  = (wg & 7) * 4 + ((wg >> 3) & 3);  // XCD-hot weight slices
    const int mg  = wg >> 5;          // sync group = batch row-block
    const int wgl = wg & 31;          // id within group
    const int m0  = mg * 16;
    const int n0  = ng * 32;

    unsigned* fB = flags + (size_t)mg * 512;              // [32] x 16 dwords
    unsigned* fC = flags + 4096 + (size_t)mg * 512;

    const int wr   = n0 + nt * 16 + lrow;    // weight-frag row (A-operand)
    const int m    = lrow;                   // owned batch row (wv<2 lanes)
    const int nb   = n0 + nt * 16 + lkg * 4; // owned 4-col base
    const int arow = m0 + lrow;              // state/x source row

    const float4 vba0 = *(const float4*)(ba0 + nb);
    const float4 vbh0 = *(const float4*)(bh0 + nb);
    const float4 vba1 = *(const float4*)(ba1 + nb);
    const float4 vbh1 = *(const float4*)(bh1 + nb);

    const f32x4 zf = {0.f, 0.f, 0.f, 0.f};
    float h0l[4] = {0,0,0,0}, s0l[4] = {0,0,0,0};
    float h1l[4] = {0,0,0,0}, s1l[4] = {0,0,0,0};

    // ---- prologue: s0(0)=0 -> zero frags; x partials for t=0 (B) and t=1 (alpha0)
    short8 frags[8];
    #pragma unroll
    for (int s = 0; s < 8; ++s)
        #pragma unroll
        for (int i = 0; i < 8; ++i) frags[s][i] = 0;
    const float* xbase = x + (size_t)arow * (TT * DD);
    f32x4 pBx  = mm_x(zf, xbase + 0 * DD, wWih0, wr, kq, lkg);   // Wih0 x_0
    f32x4 pAxN = mm_x(zf, xbase + 1 * DD, wWax0, wr, kq, lkg);   // Wax0 x_1
    f32x4 pC1  = zf;                                             // Uas1 s1(-1)=0

    for (int t = 0; t < TT; ++t) {
        u16* s0nxt = s0b + ((t + 1) & 1) * SPAN;

        // ---- B: h0(t)=tanh(pBx + Whh0 s0(t) + bh0); alpha0(t+1)=sig(pAxN +
        //      Uas0 s0(t) + ba0); s0(t+1)=a*h0+(1-a)*s0. Publish h0, s0(t+1).
        __syncthreads();   // red WAR vs D(t-1) kq0-readers
        f32x4 acc = mm_reg<8>(pBx,  frags, wWhh0, wr, kq, lkg);
        f32x4 pA  = mm_reg<8>(pAxN, frags, wUas0, wr, kq, lkg);
        red_put(red, 0, acc, nt, kq, lane);
        red_put(red, 4, pA,  nt, kq, lane);
        __syncthreads();
        if (wv < 2) {
            acc = red_get(red, 0, acc, nt, lane);
            pA  = red_get(red, 4, pA,  nt, lane);
            float hb[4];
            #pragma unroll
            for (int r = 0; r < 4; ++r) {
                hb[r] = tanhf(acc[r] + ((const float*)&vbh0)[r]);
                h0l[r] = hb[r];
            }
            agent_store64((u64*)(h0b + (size_t)(m0 + m) * HH + nb),
                          pack4(hb[0], hb[1], hb[2], hb[3]));
            if (t + 1 < TT) {
                float sb[4];
                #pragma unroll
                for (int r = 0; r < 4; ++r) {
                    float al = 1.f / (1.f + __expf(-(pA[r] + ((const float*)&vba0)[r])));
                    sb[r] = al * hb[r] + (1.f - al) * s0l[r];
                    s0l[r] = sb[r];
                }
                agent_store64((u64*)(s0nxt + (size_t)(m0 + m) * HH + nb),
                              pack4(sb[0], sb[1], sb[2], sb[3]));
            }
        }
        flag_set(fB, wgl, (unsigned)(t + 1), tid);
        flag_wait(fB, (unsigned)(t + 1), tid);

        // ---- C: alpha1(t)=sig(pC1 + Wax1 h0 + ba1); s1(t)=a1*h1(t-1)+(1-a1)*s1(t-1);
        //      publish s1(t). pD1 = Wih1 h0 (partial, reduced in D).
        short8 fh[8];
        load_frags(fh, h0b, arow, kq, lkg);
        acc = mm_reg<8>(pC1, fh, wWax1, wr, kq, lkg);
        f32x4 pD1 = mm_reg<8>(zf, fh, wWih1, wr, kq, lkg);
        red_put(red, 0, acc, nt, kq, lane);
        __syncthreads();
        if (wv < 2) {
            acc = red_get(red, 0, acc, nt, lane);
            float sb[4];
            #pragma unroll
            for (int r = 0; r < 4; ++r) {
                float al = 1.f / (1.f + __expf(-(acc[r] + ((const float*)&vba1)[r])));
                sb[r] = al * h1l[r] + (1.f - al) * s1l[r];
                s1l[r] = sb[r];
            }
            agent_store64((u64*)(s1b + (size_t)(m0 + m) * HH + nb),
                          pack4(sb[0], sb[1], sb[2], sb[3]));
        }
        flag_set(fC, wgl, (unsigned)(t + 1), tid);
        flag_wait(fC, (unsigned)(t + 1), tid);

        // ---- D: h1(t)=tanh(pD1 + Whh1 s1 + bh1); pC1 = Uas1 s1 (for C(t+1));
        //      prefetch s0(t+1) frags (flagB(t)-covered); x partials t+1/t+2.
        short8 fs1[8];
        load_frags(fs1, s1b, arow, kq, lkg);
        if (t + 1 < TT) load_frags(frags, s0nxt, arow, kq, lkg);
        acc = mm_reg<8>(pD1, fs1, wWhh1, wr, kq, lkg);
        pC1 = mm_reg<8>(zf,  fs1, wUas1, wr, kq, lkg);
        if (t + 1 < TT) pBx  = mm_x(zf, xbase + (size_t)(t + 1) * DD, wWih0, wr, kq, lkg);
        if (t + 2 < TT) pAxN = mm_x(zf, xbase + (size_t)(t + 2) * DD, wWax0, wr, kq, lkg);
        red_put(red, 0, acc, nt, kq, lane);
        __syncthreads();
        if (wv < 2) {
            acc = red_get(red, 0, acc, nt, lane);
            #pragma unroll
            for (int r = 0; r < 4; ++r) h1l[r] = tanhf(acc[r] + ((const float*)&vbh1)[r]);
        }
        // next B's leading __syncthreads covers red WAR; all span WAR windows
        // span >=1 flag-wait (writer at B(t+1) implies all passed flagC(t)).
    }

    // ---- epilogue: wv<2 lanes own (batch m0+m, cols nb..nb+3) ----
    if (wv < 2) {
        const size_t HIDB = NB, SMOB = NB + 2 * (size_t)SPAN;
        const size_t o = (size_t)(m0 + m) * HH + nb;
        *(float4*)(out + HIDB + o)        = make_float4(h0l[0], h0l[1], h0l[2], h0l[3]);
        *(float4*)(out + HIDB + SPAN + o) = make_float4(h1l[0], h1l[1], h1l[2], h1l[3]);
        *(float4*)(out + SMOB + o)        = make_float4(s0l[0], s0l[1], s0l[2], s0l[3]);
        *(float4*)(out + SMOB + SPAN + o) = make_float4(s1l[0], s1l[1], s1l[2], s1l[3]);

        // out[b] = sum_n h1[b,n]*fcW[n] + fcb; lanes m, m+16, m+32, m+48 share b.
        const float4 w4 = *(const float4*)(fcW + nb);
        float v = h1l[0] * w4.x + h1l[1] * w4.y + h1l[2] * w4.z + h1l[3] * w4.w;
        v += __shfl_xor(v, 16);
        v += __shfl_xor(v, 32);
        if (lane < 16) {
            if (ng == 0 && nt == 0) v += fcb[0];
            atomicAdd(out + m0 + lane, v);
        }
    }
}

extern "C" void kernel_launch(void* const* d_in, const int* in_sizes, int n_in,
                              void* d_out, int out_size, void* d_ws, size_t ws_size,
                              hipStream_t stream)
{
    const float* x    = (const float*)d_in[0];
    const float* Wax0 = (const float*)d_in[1];
    const float* Uas0 = (const float*)d_in[2];
    const float* ba0  = (const float*)d_in[3];
    const float* Wih0 = (const float*)d_in[4];
    const float* Whh0 = (const float*)d_in[5];
    const float* bh0  = (const float*)d_in[6];
    const float* Wax1 = (const float*)d_in[7];
    const float* Uas1 = (const float*)d_in[8];
    const float* ba1  = (const float*)d_in[9];
    const float* Wih1 = (const float*)d_in[10];
    const float* Whh1 = (const float*)d_in[11];
    const float* bh1  = (const float*)d_in[12];
    const float* fcW  = (const float*)d_in[13];
    const float* fcb  = (const float*)d_in[14];
    float* out = (float*)d_out;

    char* ws = (char*)d_ws;
    u16* s0b = (u16*)(ws + S0_OFF);
    u16* s1b = (u16*)(ws + S1_OFF);
    u16* h0b = (u16*)(ws + H0_OFF);
    unsigned* flags = (unsigned*)(ws + FL_OFF);
    u16* wbase = (u16*)(ws + W_OFF);
    u16* wUas0 = wbase + 0 * 1048576;
    u16* wWhh0 = wbase + 1 * 1048576;
    u16* wWax1 = wbase + 2 * 1048576;
    u16* wUas1 = wbase + 3 * 1048576;
    u16* wWih1 = wbase + 4 * 1048576;
    u16* wWhh1 = wbase + 5 * 1048576;
    u16* wWax0 = wbase + 6 * 1048576;
    u16* wWih0 = wbase + 6 * 1048576 + 262144;

    // zero state spans + flags + output (accumulated via atomics)
    hipMemsetAsync(d_ws, 0, W_OFF, stream);
    hipMemsetAsync(d_out, 0, (size_t)out_size * sizeof(float), stream);

    conv_weights<<<dim3(1024), dim3(256), 0, stream>>>(
        Uas0, Whh0, Wax1, Uas1, Wih1, Whh1, Wax0, Wih0, wbase);

    alphat_mfma<<<dim3(NWG), dim3(NTHR), 0, stream>>>(
        x, wUas0, wWhh0, wWax1, wUas1, wWih1, wWhh1, wWax0, wWih0,
        ba0, bh0, ba1, bh1, fcW, fcb, out, s0b, s1b, h0b, flags);
}

// Round 11
// 14115.547 us; speedup vs baseline: 2.8766x; 1.2405x over previous
//
#include <hip/hip_runtime.h>

// AlphatRNN B=128,T=512,D=256,H=1024,L=2,O=1 — bf16 MFMA persistent kernel, R11.
// R11 = R10 (flags + swapped layout, passing, 17.5ms) with the state-read
// DEDUPLICATION: waves become 8 distinct K-eighths (was 2 n-tiles x 4 K-quarters
// with both n-tile waves loading identical frags). Each wave now computes BOTH
// n-tiles over its K-slice (same MFMA count), halving issued sc1 state traffic
// 49 -> 24.6 MB/step. Reduce deepens to 8 partials x 2 nt (32KB scalar planes,
// conflict-free); owner waves 0/1 = n-tiles 0/1. All else identical to R10.

typedef unsigned short u16;
typedef unsigned long long u64;
typedef __attribute__((ext_vector_type(8))) short short8;
typedef __attribute__((ext_vector_type(4))) float f32x4;

#define NB   128
#define TT   512
#define DD   256
#define HH   1024
#define NWG  256
#define NTHR 512
#define SPAN (NB * HH)

// ---- ws layout (bytes) ----
#define S0_OFF  0u          // bf16 [2][128][1024] (parity double buffer)
#define S1_OFF  524288u     // bf16 [128][1024]
#define H0_OFF  786432u     // bf16 [128][1024]
#define FL_OFF  1048576u    // 2 flag arrays x [8 mg][32 wgl] x 64 B = 32 KB
#define W_OFF   1081344u    // bf16 weights: 6x[1024][1024], then [1024][256]x2
#define NBIG    6291456u    // 6 * 1048576

__device__ __forceinline__ u16 f2bf(float f) {   // RNE, finite inputs only
    unsigned u = __builtin_bit_cast(unsigned, f);
    return (u16)((u + 0x7fffu + ((u >> 16) & 1u)) >> 16);
}

__device__ __forceinline__ u64 agent_load64(const u64* p) {
    return __hip_atomic_load(p, __ATOMIC_RELAXED, __HIP_MEMORY_SCOPE_AGENT);
}
__device__ __forceinline__ void agent_store64(u64* p, u64 v) {
    __hip_atomic_store(p, v, __ATOMIC_RELAXED, __HIP_MEMORY_SCOPE_AGENT);
}

// Producer flag set: __syncthreads drains all waves' sc1 stores (vmcnt0 before
// s_barrier), then one RELEASE store of the monotonic step value.
__device__ __forceinline__ void flag_set(unsigned* f, int wgl, unsigned val, int tid)
{
    __syncthreads();
    if (tid == 0)
        __hip_atomic_store(f + wgl * 16, val, __ATOMIC_RELEASE,
                           __HIP_MEMORY_SCOPE_AGENT);
}
// Consumer: lanes 0..31 poll the 32 group flags in parallel (monotonic >= val).
__device__ __forceinline__ void flag_wait(unsigned* f, unsigned val, int tid)
{
    if (tid < 32)
        while (__hip_atomic_load(f + tid * 16, __ATOMIC_RELAXED,
                                 __HIP_MEMORY_SCOPE_AGENT) < val)
            __builtin_amdgcn_s_sleep(1);
    __syncthreads();
}

// State frags for one K-EIGHTH (128 k): lane(lrow,lkg) reads row m0+lrow,
// k = wv*128 + s*32 + lkg*8, s=0..3. Direct from published span via sc1.
__device__ __forceinline__ void load_frags(short8* fr, const u16* base,
                                           int row, int wv, int lkg)
{
    const u16* sp = base + ((size_t)row << 10) + wv * 128 + lkg * 8;
    #pragma unroll
    for (int s = 0; s < 4; ++s) {
        union { short8 v; u64 q[2]; } u_;
        u_.q[0] = agent_load64((const u64*)(sp + s * 32));
        u_.q[1] = agent_load64((const u64*)(sp + s * 32 + 4));
        fr[s] = u_.v;
    }
}

// a0/a1 += W[wr0/wr1, K-eighth] (x) S(frags), swapped operands (D rows = W rows
// = H-cols, D cols = batch). One wave covers BOTH n-tiles: 8 mfma / GEMM.
__device__ __forceinline__ void mm2(f32x4& a0, f32x4& a1, const short8* fr,
                                    const u16* W, int wr0, int wr1, int wv, int lkg)
{
    const u16* wp0 = W + ((size_t)wr0 << 10) + wv * 128 + lkg * 8;
    const u16* wp1 = W + ((size_t)wr1 << 10) + wv * 128 + lkg * 8;
    #pragma unroll
    for (int s = 0; s < 4; ++s) {
        a0 = __builtin_amdgcn_mfma_f32_16x16x32_bf16(
            *(const short8*)(wp0 + s * 32), fr[s], a0, 0, 0, 0);
        a1 = __builtin_amdgcn_mfma_f32_16x16x32_bf16(
            *(const short8*)(wp1 + s * 32), fr[s], a1, 0, 0, 0);
    }
}

// a0/a1 += Wx[wr0/wr1, K-eighth of 256] (x) x_row(fp32->bf16 in reg), swapped.
__device__ __forceinline__ void mmx2(f32x4& a0, f32x4& a1, const float* xrow,
                                     const u16* W, int wr0, int wr1, int wv, int lkg)
{
    const float* p = xrow + wv * 32 + lkg * 8;
    float4 a = *(const float4*)p;
    float4 b = *(const float4*)(p + 4);
    short8 v;
    v[0]=(short)f2bf(a.x); v[1]=(short)f2bf(a.y); v[2]=(short)f2bf(a.z); v[3]=(short)f2bf(a.w);
    v[4]=(short)f2bf(b.x); v[5]=(short)f2bf(b.y); v[6]=(short)f2bf(b.z); v[7]=(short)f2bf(b.w);
    const u16* wp0 = W + ((size_t)wr0 << 8) + wv * 32 + lkg * 8;
    const u16* wp1 = W + ((size_t)wr1 << 8) + wv * 32 + lkg * 8;
    a0 = __builtin_amdgcn_mfma_f32_16x16x32_bf16(*(const short8*)wp0, v, a0, 0, 0, 0);
    a1 = __builtin_amdgcn_mfma_f32_16x16x32_bf16(*(const short8*)wp1, v, a1, 0, 0, 0);
}

// 8-deep reduce planes [q][comp][nt][wave][lane]: 4B lane stride, conflict-free.
__device__ __forceinline__ void red_put(float (*red)[4][2][8][64], int q,
                                        f32x4 a0, f32x4 a1, int wv, int lane)
{
    #pragma unroll
    for (int c = 0; c < 4; ++c) {
        red[q][c][0][wv][lane] = a0[c];
        red[q][c][1][wv][lane] = a1[c];
    }
}
__device__ __forceinline__ f32x4 red_get(float (*red)[4][2][8][64], int q,
                                         int nt, int lane)
{
    f32x4 v = {0.f, 0.f, 0.f, 0.f};
    #pragma unroll
    for (int j = 0; j < 8; ++j)
        #pragma unroll
        for (int c = 0; c < 4; ++c) v[c] += red[q][c][nt][j][lane];
    return v;
}

__device__ __forceinline__ u64 pack4(float a, float b, float c, float d)
{
    return (u64)f2bf(a) | ((u64)f2bf(b) << 16) | ((u64)f2bf(c) << 32)
         | ((u64)f2bf(d) << 48);
}

__global__ void conv_weights(const float* Uas0, const float* Whh0, const float* Wax1,
                             const float* Uas1, const float* Wih1, const float* Whh1,
                             const float* Wax0, const float* Wih0, u16* dst)
{
    for (size_t i = (size_t)blockIdx.x * blockDim.x + threadIdx.x; i < 6815744u;
         i += (size_t)gridDim.x * blockDim.x) {
        const float* src; size_t off;
        if (i < NBIG) {
            int seg = (int)(i >> 20); off = i & 1048575u;
            src = seg == 0 ? Uas0 : seg == 1 ? Whh0 : seg == 2 ? Wax1
                : seg == 3 ? Uas1 : seg == 4 ? Wih1 : Whh1;
        } else {
            size_t j = i - NBIG; off = j & 262143u;
            src = (j >> 18) ? Wih0 : Wax0;
        }
        dst[i] = f2bf(src[off]);
    }
}

extern "C" __global__ void __launch_bounds__(NTHR, 1)
alphat_mfma(const float* __restrict__ x,
            const u16* __restrict__ wUas0, const u16* __restrict__ wWhh0,
            const u16* __restrict__ wWax1, const u16* __restrict__ wUas1,
            const u16* __restrict__ wWih1, const u16* __restrict__ wWhh1,
            const u16* __restrict__ wWax0, const u16* __restrict__ wWih0,
            const float* __restrict__ ba0, const float* __restrict__ bh0,
            const float* __restrict__ ba1, const float* __restrict__ bh1,
            const float* __restrict__ fcW, const float* __restrict__ fcb,
            float* __restrict__ out,
            u16* s0b, u16* s1b, u16* h0b, unsigned* flags)
{
    __shared__ float red[2][4][2][8][64];        // 32 KB reduce planes (only LDS)

    const int tid  = threadIdx.x;
    const int wv   = tid >> 6;        // wave = K-eighth; waves 0/1 own n-tiles 0/1
    const int lane = tid & 63;
    const int lrow = lane & 15;
    const int lkg  = lane >> 4;

    const int wg  = blockIdx.x;
    const int ng  = (wg & 7) * 4 + ((wg >> 3) & 3);  // XCD-hot weight slices
    const int mg  = wg >> 5;          // sync group = batch row-block
    const int wgl = wg & 31;          // id within group
    const int m0  = mg * 16;
    const int n0  = ng * 32;

    unsigned* fB = flags + (size_t)mg * 512;              // [32] x 16 dwords
    unsigned* fC = flags + 4096 + (size_t)mg * 512;

    const int wr0  = n0 + lrow;              // n-tile-0 weight row (A-operand)
    const int wr1  = n0 + 16 + lrow;         // n-tile-1 weight row
    const int arow = m0 + lrow;              // state/x source row
    const bool own = (wv < 2);               // owner waves: nt = wv
    const int m    = lrow;                   // owned batch row
    const int nb   = n0 + (wv & 1) * 16 + lkg * 4;  // owned 4-col base (wv<2)

    float4 vba0 = {0,0,0,0}, vbh0 = {0,0,0,0}, vba1 = {0,0,0,0}, vbh1 = {0,0,0,0};
    if (own) {
        vba0 = *(const float4*)(ba0 + nb);  vbh0 = *(const float4*)(bh0 + nb);
        vba1 = *(const float4*)(ba1 + nb);  vbh1 = *(const float4*)(bh1 + nb);
    }

    const f32x4 zf = {0.f, 0.f, 0.f, 0.f};
    float h0l[4] = {0,0,0,0}, s0l[4] = {0,0,0,0};
    float h1l[4] = {0,0,0,0}, s1l[4] = {0,0,0,0};

    // ---- prologue: s0(0)=0 -> zero frags; x partials for t=0 (B) and t=1 (alpha0)
    short8 frags[4];
    #pragma unroll
    for (int s = 0; s < 4; ++s)
        #pragma unroll
        for (int i = 0; i < 8; ++i) frags[s][i] = 0;
    const float* xbase = x + (size_t)arow * (TT * DD);
    f32x4 pBx0 = zf, pBx1 = zf, pAx0 = zf, pAx1 = zf;
    f32x4 pC10 = zf, pC11 = zf, pD10 = zf, pD11 = zf;
    mmx2(pBx0, pBx1, xbase + 0 * DD, wWih0, wr0, wr1, wv, lkg);  // Wih0 x_0
    mmx2(pAx0, pAx1, xbase + 1 * DD, wWax0, wr0, wr1, wv, lkg);  // Wax0 x_1

    for (int t = 0; t < TT; ++t) {
        u16* s0nxt = s0b + ((t + 1) & 1) * SPAN;

        // ---- B: h0(t)=tanh(pBx + Whh0 s0(t) + bh0); alpha0(t+1)=sig(pAx +
        //      Uas0 s0(t) + ba0); s0(t+1)=a*h0+(1-a)*s0. Publish h0, s0(t+1).
        __syncthreads();   // red WAR vs D(t-1) readers
        f32x4 a0 = pBx0, a1 = pBx1, q0 = pAx0, q1 = pAx1;
        mm2(a0, a1, frags, wWhh0, wr0, wr1, wv, lkg);
        mm2(q0, q1, frags, wUas0, wr0, wr1, wv, lkg);
        red_put(red, 0, a0, a1, wv, lane);
        red_put(red, 1, q0, q1, wv, lane);
        __syncthreads();
        if (own) {
            f32x4 acc = red_get(red, 0, wv, lane);
            f32x4 pA  = red_get(red, 1, wv, lane);
            float hb[4];
            #pragma unroll
            for (int r = 0; r < 4; ++r) {
                hb[r] = tanhf(acc[r] + ((const float*)&vbh0)[r]);
                h0l[r] = hb[r];
            }
            agent_store64((u64*)(h0b + (size_t)(m0 + m) * HH + nb),
                          pack4(hb[0], hb[1], hb[2], hb[3]));
            if (t + 1 < TT) {
                float sb[4];
                #pragma unroll
                for (int r = 0; r < 4; ++r) {
                    float al = 1.f / (1.f + __expf(-(pA[r] + ((const float*)&vba0)[r])));
                    sb[r] = al * hb[r] + (1.f - al) * s0l[r];
                    s0l[r] = sb[r];
                }
                agent_store64((u64*)(s0nxt + (size_t)(m0 + m) * HH + nb),
                              pack4(sb[0], sb[1], sb[2], sb[3]));
            }
        }
        flag_set(fB, wgl, (unsigned)(t + 1), tid);
        flag_wait(fB, (unsigned)(t + 1), tid);

        // ---- C: alpha1(t)=sig(pC1 + Wax1 h0 + ba1); s1(t)=a1*h1(t-1)+(1-a1)*s1(t-1);
        //      publish s1(t). pD1 = Wih1 h0 (partial, reduced in D).
        short8 fh[4];
        load_frags(fh, h0b, arow, wv, lkg);
        f32x4 c0 = pC10, c1 = pC11;
        mm2(c0, c1, fh, wWax1, wr0, wr1, wv, lkg);
        pD10 = zf; pD11 = zf;
        mm2(pD10, pD11, fh, wWih1, wr0, wr1, wv, lkg);
        red_put(red, 0, c0, c1, wv, lane);
        __syncthreads();
        if (own) {
            f32x4 acc = red_get(red, 0, wv, lane);
            float sb[4];
            #pragma unroll
            for (int r = 0; r < 4; ++r) {
                float al = 1.f / (1.f + __expf(-(acc[r] + ((const float*)&vba1)[r])));
                sb[r] = al * h1l[r] + (1.f - al) * s1l[r];
                s1l[r] = sb[r];
            }
            agent_store64((u64*)(s1b + (size_t)(m0 + m) * HH + nb),
                          pack4(sb[0], sb[1], sb[2], sb[3]));
        }
        flag_set(fC, wgl, (unsigned)(t + 1), tid);
        flag_wait(fC, (unsigned)(t + 1), tid);

        // ---- D: h1(t)=tanh(pD1 + Whh1 s1 + bh1); pC1 = Uas1 s1 (for C(t+1));
        //      prefetch s0(t+1) frags (flagB(t)-covered); x partials t+1/t+2.
        short8 fs1[4];
        load_frags(fs1, s1b, arow, wv, lkg);
        if (t + 1 < TT) load_frags(frags, s0nxt, arow, wv, lkg);
        f32x4 d0 = pD10, d1 = pD11;
        mm2(d0, d1, fs1, wWhh1, wr0, wr1, wv, lkg);
        pC10 = zf; pC11 = zf;
        mm2(pC10, pC11, fs1, wUas1, wr0, wr1, wv, lkg);
        if (t + 1 < TT) {
            pBx0 = zf; pBx1 = zf;
            mmx2(pBx0, pBx1, xbase + (size_t)(t + 1) * DD, wWih0, wr0, wr1, wv, lkg);
        }
        if (t + 2 < TT) {
            pAx0 = zf; pAx1 = zf;
            mmx2(pAx0, pAx1, xbase + (size_t)(t + 2) * DD, wWax0, wr0, wr1, wv, lkg);
        }
        red_put(red, 0, d0, d1, wv, lane);
        __syncthreads();
        if (own) {
            f32x4 acc = red_get(red, 0, wv, lane);
            #pragma unroll
            for (int r = 0; r < 4; ++r) h1l[r] = tanhf(acc[r] + ((const float*)&vbh1)[r]);
        }
        // next B's leading __syncthreads covers red WAR; all span WAR windows
        // span >=1 flag-wait (writer at B(t+1) implies all passed flagC(t)).
    }

    // ---- epilogue: owner waves (wv<2) hold (batch m0+m, cols nb..nb+3) ----
    if (own) {
        const size_t HIDB = NB, SMOB = NB + 2 * (size_t)SPAN;
        const size_t o = (size_t)(m0 + m) * HH + nb;
        *(float4*)(out + HIDB + o)        = make_float4(h0l[0], h0l[1], h0l[2], h0l[3]);
        *(float4*)(out + HIDB + SPAN + o) = make_float4(h1l[0], h1l[1], h1l[2], h1l[3]);
        *(float4*)(out + SMOB + o)        = make_float4(s0l[0], s0l[1], s0l[2], s0l[3]);
        *(float4*)(out + SMOB + SPAN + o) = make_float4(s1l[0], s1l[1], s1l[2], s1l[3]);

        // out[b] = sum_n h1[b,n]*fcW[n] + fcb; lanes m, m+16, m+32, m+48 share b.
        const float4 w4 = *(const float4*)(fcW + nb);
        float v = h1l[0] * w4.x + h1l[1] * w4.y + h1l[2] * w4.z + h1l[3] * w4.w;
        v += __shfl_xor(v, 16);
        v += __shfl_xor(v, 32);
        if (lane < 16) {
            if (ng == 0 && wv == 0) v += fcb[0];
            atomicAdd(out + m0 + lane, v);
        }
    }
}

extern "C" void kernel_launch(void* const* d_in, const int* in_sizes, int n_in,
                              void* d_out, int out_size, void* d_ws, size_t ws_size,
                              hipStream_t stream)
{
    const float* x    = (const float*)d_in[0];
    const float* Wax0 = (const float*)d_in[1];
    const float* Uas0 = (const float*)d_in[2];
    const float* ba0  = (const float*)d_in[3];
    const float* Wih0 = (const float*)d_in[4];
    const float* Whh0 = (const float*)d_in[5];
    const float* bh0  = (const float*)d_in[6];
    const float* Wax1 = (const float*)d_in[7];
    const float* Uas1 = (const float*)d_in[8];
    const float* ba1  = (const float*)d_in[9];
    const float* Wih1 = (const float*)d_in[10];
    const float* Whh1 = (const float*)d_in[11];
    const float* bh1  = (const float*)d_in[12];
    const float* fcW  = (const float*)d_in[13];
    const float* fcb  = (const float*)d_in[14];
    float* out = (float*)d_out;

    char* ws = (char*)d_ws;
    u16* s0b = (u16*)(ws + S0_OFF);
    u16* s1b = (u16*)(ws + S1_OFF);
    u16* h0b = (u16*)(ws + H0_OFF);
    unsigned* flags = (unsigned*)(ws + FL_OFF);
    u16* wbase = (u16*)(ws + W_OFF);
    u16* wUas0 = wbase + 0 * 1048576;
    u16* wWhh0 = wbase + 1 * 1048576;
    u16* wWax1 = wbase + 2 * 1048576;
    u16* wUas1 = wbase + 3 * 1048576;
    u16* wWih1 = wbase + 4 * 1048576;
    u16* wWhh1 = wbase + 5 * 1048576;
    u16* wWax0 = wbase + 6 * 1048576;
    u16* wWih0 = wbase + 6 * 1048576 + 262144;

    // zero state spans + flags + output (accumulated via atomics)
    hipMemsetAsync(d_ws, 0, W_OFF, stream);
    hipMemsetAsync(d_out, 0, (size_t)out_size * sizeof(float), stream);

    conv_weights<<<dim3(1024), dim3(256), 0, stream>>>(
        Uas0, Whh0, Wax1, Uas1, Wih1, Whh1, Wax0, Wih0, wbase);

    alphat_mfma<<<dim3(NWG), dim3(NTHR), 0, stream>>>(
        x, wUas0, wWhh0, wWax1, wUas1, wWih1, wWhh1, wWax0, wWih0,
        ba0, bh0, ba1, bh1, fcW, fcb, out, s0b, s1b, h0b, flags);
}